// Round 3
// baseline (10581.488 us; speedup 1.0000x reference)
//
#include <hip/hip_runtime.h>
#include <hip/hip_cooperative_groups.h>
#include <math.h>

namespace cg = cooperative_groups;

#define N_V 5000
#define N_F 10000
#define NNZ 480000
#define LAYERS 30

struct Params {
  const float* inputs;
  const int* Di_rows; const int* Di_cols; const float* Di_vals;
  const int* DiA_rows; const int* DiA_cols; const float* DiA_vals;
  const float *W_in,*b_in,*g0,*be0,*W0,*b0,*g1,*be1,*Wl1,*bl1,*g2,*be2,*W_out,*b_out;
  float *v_raw,*elu_v,*elu_f,*Dv,*DAf,*st,*oddb,*out;
  int *Di_ptr,*Di_cur,*Di_colss; float* Di_valss;
  int *DA_ptr,*DA_cur,*DA_colss; float* DA_valss;
  int *bsumDi,*bsumDA;
};

__device__ __forceinline__ float eluf(float x){ return x>0.f ? x : expm1f(x); }

// ---------------- init: zero stats slots, elu_f, histograms ----------------
__device__ void zero_stage(const Params& P){
  int stride = gridDim.x*256;
  int base = blockIdx.x*256 + threadIdx.x;
  for(int i=base; i<64*512; i+=stride) P.st[i]=0.f;
  for(int i=base; i<N_F*128; i+=stride) P.elu_f[i]=0.f;
  for(int i=base; i<40000; i+=stride) P.Di_cur[i]=0;
  for(int i=base; i<20000; i+=stride) P.DA_cur[i]=0;
}

__device__ void hist_stage(const Params& P){
  int stride = gridDim.x*256;
  for(int e=blockIdx.x*256+threadIdx.x; e<NNZ; e+=stride){
    atomicAdd(&P.Di_cur[P.Di_rows[e]],1);
    atomicAdd(&P.DA_cur[P.DiA_rows[e]],1);
  }
}

__device__ void chunkscan_stage(const Params& P, float* poolf){
  int* ish = (int*)poolf;
  int b = blockIdx.x;
  const int nchDi = 157, nchDA = 79;
  int tid = threadIdx.x;
  int* hist; int* optr; int n; int cb; int* bs;
  if(b < nchDi){ hist=P.Di_cur; optr=P.Di_ptr; n=40000; cb=b; bs=P.bsumDi; }
  else if(b < nchDi+nchDA){ hist=P.DA_cur; optr=P.DA_ptr; n=20000; cb=b-nchDi; bs=P.bsumDA; }
  else return;
  int i = cb*256 + tid;
  int v = (i<n)? hist[i] : 0;
  ish[tid]=v; __syncthreads();
  for(int off=1; off<256; off<<=1){
    int t = (tid>=off)? ish[tid-off]:0;
    __syncthreads(); ish[tid]+=t; __syncthreads();
  }
  if(i<n) optr[i] = ish[tid]-v;         // exclusive within chunk
  if(tid==255) bs[cb]=ish[255];
}

__device__ void topscan_stage(const Params& P, float* poolf){
  int* ish=(int*)poolf;
  int tid=threadIdx.x;
  if(blockIdx.x==0){
    int v = (tid<157)? P.bsumDi[tid]:0;
    ish[tid]=v; __syncthreads();
    for(int off=1; off<256; off<<=1){
      int t=(tid>=off)?ish[tid-off]:0; __syncthreads(); ish[tid]+=t; __syncthreads();
    }
    if(tid<157) P.bsumDi[tid]=ish[tid]-v;
  } else if(blockIdx.x==1){
    int v = (tid<79)? P.bsumDA[tid]:0;
    ish[tid]=v; __syncthreads();
    for(int off=1; off<256; off<<=1){
      int t=(tid>=off)?ish[tid-off]:0; __syncthreads(); ish[tid]+=t; __syncthreads();
    }
    if(tid<79) P.bsumDA[tid]=ish[tid]-v;
  }
}

__device__ void addback_stage(const Params& P){
  int stride=gridDim.x*256;
  int base=blockIdx.x*256+threadIdx.x;
  for(int i=base;i<40000;i+=stride){ int v=P.Di_ptr[i]+P.bsumDi[i>>8]; P.Di_ptr[i]=v; P.Di_cur[i]=v; }
  for(int i=base;i<20000;i+=stride){ int v=P.DA_ptr[i]+P.bsumDA[i>>8]; P.DA_ptr[i]=v; P.DA_cur[i]=v; }
  if(base==0){ P.Di_ptr[40000]=NNZ; P.DA_ptr[20000]=NNZ; }
}

__device__ void scatter_stage(const Params& P){
  int stride=gridDim.x*256;
  for(int e=blockIdx.x*256+threadIdx.x;e<NNZ;e+=stride){
    int r=P.Di_rows[e]; int pos=atomicAdd(&P.Di_cur[r],1);
    P.Di_colss[pos]=P.Di_cols[e]; P.Di_valss[pos]=P.Di_vals[e];
    r=P.DiA_rows[e]; pos=atomicAdd(&P.DA_cur[r],1);
    P.DA_colss[pos]=P.DiA_cols[e]; P.DA_valss[pos]=P.DiA_vals[e];
  }
}

// ---------------- conv1 (+ elu_v stats -> S1 half1) + odd-bias precompute ----
__device__ void conv1_stage(const Params& P, float* pool){
  int tid = threadIdx.x;
  float ls=0.f, ls2=0.f;
  int stride = gridDim.x*256;
  for(int idx = blockIdx.x*256+tid; idx < N_V*128; idx += stride){
    int n = idx>>7, c = idx&127;
    float v = P.b_in[c] + P.inputs[n*3]*P.W_in[c]
            + P.inputs[n*3+1]*P.W_in[128+c] + P.inputs[n*3+2]*P.W_in[256+c];
    P.v_raw[idx] = v;
    float ev = eluf(v);
    P.elu_v[idx] = ev;
    ls += ev; ls2 += ev*ev;
  }
  float* S1 = P.st + 512;            // layer0 BN1 slot, first half
  int ch = tid & 127;
  pool[tid]=ls; __syncthreads();
  if(tid<128) atomicAdd(&S1[ch], pool[tid]+pool[tid+128]);
  __syncthreads();
  pool[tid]=ls2; __syncthreads();
  if(tid<128) atomicAdd(&S1[256+ch], pool[tid]+pool[tid+128]);
  __syncthreads();
  // odd-layer broadcast-channel bias: oddb[i*256+m*128+j] = sum_k be[i*256+128+k]*W[i][(128+k)][j]
  for(int item = blockIdx.x*256+tid; item < LAYERS*2*128; item += stride){
    int i = item >> 8;
    int m = (item >> 7) & 1;
    int j = item & 127;
    const float* be = m ? P.be1 : P.be0;
    const float* W  = m ? P.Wl1 : P.W0;
    const float* wp = W + (size_t)i*32768 + 128*128 + j;
    const float* bp = be + i*256 + 128;
    float s = 0.f;
    for(int k=0;k<128;++k) s += bp[k]*wp[k*128];
    P.oddb[item] = s;
  }
}

// ---------------- SpMM (CSR gather) + channel stats -> slot half2 ----------
__device__ void spmm_stage(const int* ptr, const int* colss, const float* valss,
                           const float* x, float* y, int nrows,
                           float* stslot, float* pool){
  int tid = threadIdx.x;
  int total = nrows*32;
  int stride = gridDim.x*256;
  float ls=0.f, ls2=0.f;
  for(int idx = blockIdx.x*256 + tid; idx < total; idx += stride){
    int row = idx>>5, j = idx&31;
    int s = ptr[row], e = ptr[row+1];
    float acc = 0.f;
    for(int i=s;i<e;++i) acc += valss[i]*x[colss[i]*32 + j];
    y[idx] = acc;
    ls += acc; ls2 += acc*acc;
  }
  // channel = ((row&3)<<5)|j = idx&127 = tid&127 (stride%128==0 keeps it invariant)
  int ch = tid & 127;
  pool[tid] = ls; __syncthreads();
  if(tid<128) atomicAdd(&stslot[128+ch], pool[tid]+pool[tid+128]);
  __syncthreads();
  pool[tid] = ls2; __syncthreads();
  if(tid<128) atomicAdd(&stslot[384+ch], pool[tid]+pool[tid+128]);
  __syncthreads();
}

// ---------------- GEMM with BN folded into A-staging + fused stats --------
// out[M,128] = BN(concat(A0,A1)) @ W + bias (+bias2) (+resid)
// tile 16 rows x 128 cols, K-chunks of 16. In-place safe (per-tile row ownership).
__device__ void gemm_stage(const float* A0, const float* A1,
                           const float* st, float invM,
                           const float* gvec, const float* bevec,
                           const float* W, const float* bias, const float* bias2,
                           const float* resid, float* out_raw, float* out_elu,
                           float* stE, float* stR, int M, int K, float* pool){
  float* As = pool;            // [16][17]
  float* Ws = pool + 272;      // [16][128], reused as stats scratch
  int tid = threadIdx.x;
  int tx = tid & 15, ty = tid >> 4;
  int lk = tid & 15, lr = tid >> 4;
  int ntiles = (M+15)>>4;
  for(int t = blockIdx.x; t < ntiles; t += gridDim.x){
    int m0 = t<<4;
    float acc[8] = {0,0,0,0,0,0,0,0};
    for(int kb=0; kb<K; kb+=16){
      int kg = kb + lk;
      float mean = st[kg]*invM;
      float var  = fmaxf(st[256+kg]*invM - mean*mean, 0.f);
      float aa   = gvec[kg]*rsqrtf(var + 1e-5f);
      float bb   = bevec[kg];
      const float* src = A0; int kk = kg;
      if(A1 && kg >= 128){ src = A1; kk = kg-128; }
      int row = m0 + lr;
      float xv = (row < M) ? src[row*128 + kk] : 0.f;
      As[lk*17 + lr] = (row < M) ? ((xv-mean)*aa + bb) : 0.f;
      #pragma unroll
      for(int p=0;p<8;++p){
        int idx = tid + p*256;
        int kk2 = idx>>7, j = idx&127;
        Ws[kk2*128 + j] = W[(kb+kk2)*128 + j];
      }
      __syncthreads();
      #pragma unroll
      for(int kk2=0;kk2<16;++kk2){
        float a = As[kk2*17 + ty];
        const float4 w0 = *(const float4*)&Ws[kk2*128 + tx*8];
        const float4 w1 = *(const float4*)&Ws[kk2*128 + tx*8 + 4];
        acc[0] += a*w0.x; acc[1] += a*w0.y; acc[2] += a*w0.z; acc[3] += a*w0.w;
        acc[4] += a*w1.x; acc[5] += a*w1.y; acc[6] += a*w1.z; acc[7] += a*w1.w;
      }
      __syncthreads();
    }
    int row = m0 + ty;
    bool ok = row < M;
    float vraw[8], velu[8];
    #pragma unroll
    for(int c=0;c<8;++c){
      int j = tx*8 + c;
      float v = acc[c] + bias[j];
      if(bias2) v += bias2[j];
      if(resid && ok) v += resid[row*128 + j];
      vraw[c] = v; velu[c] = eluf(v);
    }
    if(ok){
      if(out_raw){
        float4* p0 = (float4*)&out_raw[row*128 + tx*8];
        p0[0] = make_float4(vraw[0],vraw[1],vraw[2],vraw[3]);
        p0[1] = make_float4(vraw[4],vraw[5],vraw[6],vraw[7]);
      }
      if(out_elu){
        float4* p0 = (float4*)&out_elu[row*128 + tx*8];
        p0[0] = make_float4(velu[0],velu[1],velu[2],velu[3]);
        p0[1] = make_float4(velu[4],velu[5],velu[6],velu[7]);
      }
    }
    if(stE){
      #pragma unroll
      for(int c=0;c<8;++c) Ws[ty*128 + tx*8 + c] = ok ? velu[c] : 0.f;
      __syncthreads();
      if(tid<128){ float s=0; for(int r=0;r<16;++r) s += Ws[r*128+tid]; atomicAdd(&stE[tid], s); }
      __syncthreads();
      #pragma unroll
      for(int c=0;c<8;++c){ float v = ok? velu[c]:0.f; Ws[ty*128 + tx*8 + c] = v*v; }
      __syncthreads();
      if(tid<128){ float s=0; for(int r=0;r<16;++r) s += Ws[r*128+tid]; atomicAdd(&stE[256+tid], s); }
      __syncthreads();
    }
    if(stR){
      #pragma unroll
      for(int c=0;c<8;++c) Ws[ty*128 + tx*8 + c] = ok ? vraw[c] : 0.f;
      __syncthreads();
      if(tid<128){ float s=0; for(int r=0;r<16;++r) s += Ws[r*128+tid]; atomicAdd(&stR[tid], s); }
      __syncthreads();
      #pragma unroll
      for(int c=0;c<8;++c){ float v = ok? vraw[c]:0.f; Ws[ty*128 + tx*8 + c] = v*v; }
      __syncthreads();
      if(tid<128){ float s=0; for(int r=0;r<16;++r) s += Ws[r*128+tid]; atomicAdd(&stR[256+tid], s); }
      __syncthreads();
    }
  }
}

// ---------------- final conv2: BN(v) @ W_out + b_out, elu ------------------
__device__ void final_stage(const Params& P, float* pool){
  const float* S = P.st + 62*512;      // raw v stats
  int tid = threadIdx.x;
  int half = tid>>7; int k = tid&127;
  float mean = S[k]*(1.f/N_V);
  float var = fmaxf(S[256+k]*(1.f/N_V) - mean*mean, 0.f);
  float aa = P.g2[k]*rsqrtf(var+1e-5f);
  float scale = aa*P.W_out[k];
  float cons = (P.be2[k]-mean*aa)*P.W_out[k];
  for(int r0 = blockIdx.x*2; r0 < N_V; r0 += gridDim.x*2){
    int r = r0 + half;                 // N_V even -> always < N_V
    float val = P.v_raw[r*128+k]*scale + cons;
    pool[tid]=val; __syncthreads();
    for(int s=64;s>=1;s>>=1){ if(k<s) pool[tid]+=pool[tid+s]; __syncthreads(); }
    if(k==0) P.out[r] = eluf(pool[tid] + P.b_out[0]);
    __syncthreads();
  }
}

// ---------------- the megakernel ----------------
__global__ __launch_bounds__(256,4) void mega(Params P){
  __shared__ float pool[2320];
  cg::grid_group grid = cg::this_grid();
  zero_stage(P);
  grid.sync();
  hist_stage(P);
  grid.sync();
  chunkscan_stage(P,pool);
  grid.sync();
  topscan_stage(P,pool);
  grid.sync();
  addback_stage(P);
  grid.sync();
  scatter_stage(P);
  conv1_stage(P,pool);
  grid.sync();
  for(int i=0;i<LAYERS;++i){
    if((i&1)==0){
      float* S0  = P.st + (2*i)*512;
      float* S1b = P.st + (2*i+1)*512;
      spmm_stage(P.Di_ptr,P.Di_colss,P.Di_valss,P.elu_v,P.Dv,40000,S0,pool);
      grid.sync();
      gemm_stage(P.elu_f,P.Dv, S0, 1.f/N_F, P.g0+i*256, P.be0+i*256,
                 P.W0+(size_t)i*32768, P.b0+i*128, nullptr,
                 nullptr, nullptr, P.elu_f,
                 P.st+(size_t)(2*(i+2))*512, nullptr, N_F, 256, pool);
      grid.sync();
      spmm_stage(P.DA_ptr,P.DA_colss,P.DA_valss,P.elu_f,P.DAf,20000,S1b,pool);
      grid.sync();
      gemm_stage(P.elu_v,P.DAf, S1b, 1.f/N_V, P.g1+i*256, P.be1+i*256,
                 P.Wl1+(size_t)i*32768, P.bl1+i*128, nullptr,
                 P.v_raw, P.v_raw, P.elu_v,
                 P.st+(size_t)(2*(i+1))*512, nullptr, N_V, 256, pool);
      grid.sync();
    } else {
      float* S0  = P.st + (2*i)*512;
      float* S1b = P.st + (2*i+1)*512;
      float* elu_x1 = P.Dv;            // reuse (Dv idle on odd layers)
      gemm_stage(P.elu_v,nullptr, S0, 1.f/N_V, P.g0+i*256, P.be0+i*256,
                 P.W0+(size_t)i*32768, P.b0+i*128, P.oddb+i*256,
                 nullptr, nullptr, elu_x1,
                 S1b, nullptr, N_V, 128, pool);
      grid.sync();
      float* stE = (i==LAYERS-1)? nullptr : P.st+(size_t)(2*i+3)*512;
      float* stR = (i==LAYERS-1)? P.st+(size_t)62*512 : nullptr;
      gemm_stage(elu_x1,nullptr, S1b, 1.f/N_V, P.g1+i*256, P.be1+i*256,
                 P.Wl1+(size_t)i*32768, P.bl1+i*128, P.oddb+i*256+128,
                 P.v_raw, P.v_raw, P.elu_v,
                 stE, stR, N_V, 128, pool);
      grid.sync();
    }
  }
  final_stage(P,pool);
}

extern "C" void kernel_launch(void* const* d_in, const int* in_sizes, int n_in,
                              void* d_out, int out_size, void* d_ws, size_t ws_size,
                              hipStream_t stream){
  Params p;
  p.inputs  = (const float*)d_in[0];
  p.Di_rows = (const int*)d_in[2];
  p.Di_cols = (const int*)d_in[3];
  p.Di_vals = (const float*)d_in[4];
  p.DiA_rows= (const int*)d_in[5];
  p.DiA_cols= (const int*)d_in[6];
  p.DiA_vals= (const float*)d_in[7];
  p.W_in = (const float*)d_in[8];  p.b_in = (const float*)d_in[9];
  p.g0  = (const float*)d_in[10];  p.be0 = (const float*)d_in[11];
  p.W0  = (const float*)d_in[12];  p.b0  = (const float*)d_in[13];
  p.g1  = (const float*)d_in[14];  p.be1 = (const float*)d_in[15];
  p.Wl1 = (const float*)d_in[16];  p.bl1 = (const float*)d_in[17];
  p.g2  = (const float*)d_in[18];  p.be2 = (const float*)d_in[19];
  p.W_out = (const float*)d_in[20]; p.b_out = (const float*)d_in[21];

  float* ws = (float*)d_ws;
  p.v_raw = ws;
  p.elu_v = ws + 640000;
  p.elu_f = ws + 1280000;
  p.Dv    = ws + 2560000;
  p.DAf   = ws + 3840000;
  p.st    = ws + 4480000;          // 64 slots x 512
  p.oddb  = ws + 4512768;          // 30*2*128
  p.Di_ptr  = (int*)(ws + 4520448);   // 40001
  p.Di_cur  = (int*)(ws + 4560449);   // 40000
  p.DA_ptr  = (int*)(ws + 4600449);   // 20001
  p.DA_cur  = (int*)(ws + 4620450);   // 20000
  p.Di_colss= (int*)(ws + 4640450);   // 480000
  p.Di_valss=        ws + 5120450;    // 480000
  p.DA_colss= (int*)(ws + 5600450);   // 480000
  p.DA_valss=        ws + 6080450;    // 480000
  p.bsumDi  = (int*)(ws + 6560450);   // 256
  p.bsumDA  = (int*)(ws + 6560706);   // 128
  p.out = (float*)d_out;

  int nb = 0;
  hipOccupancyMaxActiveBlocksPerMultiprocessor(&nb, (const void*)mega, 256, 0);
  if(nb < 1) nb = 1;
  int grid = nb * 256;               // 256 CUs on MI355X
  if(grid > 1024) grid = 1024;
  if(grid < 256)  grid = 256;

  void* args[] = { &p };
  hipLaunchCooperativeKernel((const void*)mega, dim3(grid), dim3(256), args, 0, stream);
}

// Round 4
// 3821.695 us; speedup vs baseline: 2.7688x; 2.7688x over previous
//
#include <hip/hip_runtime.h>
#include <math.h>

#define N_V 5000
#define N_F 10000
#define NNZ 480000
#define LAYERS 30

__device__ __forceinline__ float eluf(float x){ return x>0.f ? x : expm1f(x); }

// ---------------- CSR build ----------------
__global__ void hist_both(const int* __restrict__ Di_rows, const int* __restrict__ DiA_rows,
                          int* __restrict__ Di_cur, int* __restrict__ DA_cur){
  int e = blockIdx.x*256 + threadIdx.x;
  if(e < NNZ){
    atomicAdd(&Di_cur[Di_rows[e]], 1);
    atomicAdd(&DA_cur[DiA_rows[e]], 1);
  }
}

// 236 blocks: 157 for Di (40000), 79 for DA (20000)
__global__ void chunkscan(const int* __restrict__ Di_cur, int* __restrict__ Di_ptr,
                          const int* __restrict__ DA_cur, int* __restrict__ DA_ptr,
                          int* __restrict__ bsumDi, int* __restrict__ bsumDA){
  __shared__ int ish[256];
  int b = blockIdx.x, tid = threadIdx.x;
  const int nchDi = 157;
  const int* hist; int* optr; int n; int cb; int* bs;
  if(b < nchDi){ hist=Di_cur; optr=Di_ptr; n=40000; cb=b; bs=bsumDi; }
  else { hist=DA_cur; optr=DA_ptr; n=20000; cb=b-nchDi; bs=bsumDA; }
  int i = cb*256 + tid;
  int v = (i<n)? hist[i] : 0;
  ish[tid]=v; __syncthreads();
  for(int off=1; off<256; off<<=1){
    int t = (tid>=off)? ish[tid-off] : 0;
    __syncthreads(); ish[tid]+=t; __syncthreads();
  }
  if(i<n) optr[i] = ish[tid]-v;
  if(tid==255) bs[cb]=ish[255];
}

__global__ void topscan(int* __restrict__ bsumDi, int* __restrict__ bsumDA){
  __shared__ int ish[256];
  int tid=threadIdx.x;
  int* bs = (blockIdx.x==0) ? bsumDi : bsumDA;
  int n  = (blockIdx.x==0) ? 157 : 79;
  int v = (tid<n)? bs[tid] : 0;
  ish[tid]=v; __syncthreads();
  for(int off=1; off<256; off<<=1){
    int t=(tid>=off)? ish[tid-off]:0;
    __syncthreads(); ish[tid]+=t; __syncthreads();
  }
  if(tid<n) bs[tid]=ish[tid]-v;
}

__global__ void addback(int* __restrict__ Di_ptr, int* __restrict__ Di_cur,
                        const int* __restrict__ bsumDi,
                        int* __restrict__ DA_ptr, int* __restrict__ DA_cur,
                        const int* __restrict__ bsumDA){
  int stride = gridDim.x*256;
  int base = blockIdx.x*256 + threadIdx.x;
  for(int i=base;i<40000;i+=stride){ int v=Di_ptr[i]+bsumDi[i>>8]; Di_ptr[i]=v; Di_cur[i]=v; }
  for(int i=base;i<20000;i+=stride){ int v=DA_ptr[i]+bsumDA[i>>8]; DA_ptr[i]=v; DA_cur[i]=v; }
  if(base==0){ Di_ptr[40000]=NNZ; DA_ptr[20000]=NNZ; }
}

__global__ void scatter_both(const int* __restrict__ Di_rows, const int* __restrict__ Di_cols,
                             const float* __restrict__ Di_vals, int* __restrict__ Di_cur,
                             int* __restrict__ Di_colss, float* __restrict__ Di_valss,
                             const int* __restrict__ DiA_rows, const int* __restrict__ DiA_cols,
                             const float* __restrict__ DiA_vals, int* __restrict__ DA_cur,
                             int* __restrict__ DA_colss, float* __restrict__ DA_valss){
  int e = blockIdx.x*256 + threadIdx.x;
  if(e >= NNZ) return;
  int r = Di_rows[e]; int pos = atomicAdd(&Di_cur[r],1);
  Di_colss[pos]=Di_cols[e]; Di_valss[pos]=Di_vals[e];
  r = DiA_rows[e]; pos = atomicAdd(&DA_cur[r],1);
  DA_colss[pos]=DiA_cols[e]; DA_valss[pos]=DiA_vals[e];
}

// ---------------- conv1 (+ elu stats -> st1 first half) + odd-bias precompute ----
__global__ void conv1_kernel(const float* __restrict__ in, const float* __restrict__ W_in,
                             const float* __restrict__ b_in,
                             const float* __restrict__ be0, const float* __restrict__ W0,
                             const float* __restrict__ be1, const float* __restrict__ Wl1,
                             float* __restrict__ v_raw, float* __restrict__ elu_v,
                             float* __restrict__ st1, float* __restrict__ oddb){
  __shared__ float pool[256];
  int tid = threadIdx.x;
  int stride = gridDim.x*256;
  float ls=0.f, ls2=0.f;
  for(int idx = blockIdx.x*256+tid; idx < N_V*128; idx += stride){
    int n = idx>>7, c = idx&127;
    float v = b_in[c] + in[n*3]*W_in[c] + in[n*3+1]*W_in[128+c] + in[n*3+2]*W_in[256+c];
    v_raw[idx] = v;
    float ev = eluf(v);
    elu_v[idx] = ev;
    ls += ev; ls2 += ev*ev;
  }
  int ch = tid & 127;   // stride % 128 == 0 keeps channel invariant
  pool[tid]=ls; __syncthreads();
  if(tid<128) atomicAdd(&st1[ch], pool[tid]+pool[tid+128]);
  __syncthreads();
  pool[tid]=ls2; __syncthreads();
  if(tid<128) atomicAdd(&st1[256+ch], pool[tid]+pool[tid+128]);
  // oddb[i*256+m*128+j] = sum_k be_m[i*256+128+k] * W_m[i][(128+k)*128 + j]
  for(int item = blockIdx.x*256+tid; item < LAYERS*2*128; item += stride){
    int i = item >> 8;
    int m = (item >> 7) & 1;
    int j = item & 127;
    const float* be = m ? be1 : be0;
    const float* W  = m ? Wl1 : W0;
    const float* wp = W + (size_t)i*32768 + 128*128 + j;
    const float* bp = be + i*256 + 128;
    float s = 0.f;
    for(int k=0;k<128;++k) s += bp[k]*wp[k*128];
    oddb[item] = s;
  }
}

// ---------------- SpMM (CSR gather) + fused channel stats -> slot second half ----
__global__ __launch_bounds__(256) void spmm_bn(
    const int* __restrict__ ptr, const int* __restrict__ colss, const float* __restrict__ valss,
    const float* __restrict__ x, float* __restrict__ y, int nrows, float* __restrict__ stslot){
  __shared__ float pool[256];
  int tid = threadIdx.x;
  int total = nrows*32;
  int stride = gridDim.x*256;
  float ls=0.f, ls2=0.f;
  for(int idx = blockIdx.x*256 + tid; idx < total; idx += stride){
    int row = idx>>5, j = idx&31;
    int s = ptr[row], e = ptr[row+1];
    float acc = 0.f;
    for(int i=s;i<e;++i) acc += valss[i]*x[(colss[i]<<5) + j];
    y[idx] = acc;
    ls += acc; ls2 += acc*acc;
  }
  int ch = tid & 127;
  pool[tid] = ls; __syncthreads();
  if(tid<128) atomicAdd(&stslot[128+ch], pool[tid]+pool[tid+128]);
  __syncthreads();
  pool[tid] = ls2; __syncthreads();
  if(tid<128) atomicAdd(&stslot[384+ch], pool[tid]+pool[tid+128]);
}

// ---------------- GEMM with BN folded into A-staging + fused output stats --------
// out[M,128] = BN(concat(A0,A1)) @ W + bias (+bias2) (+resid); tile 32x128, block 256
__global__ __launch_bounds__(256) void gemm_bn(
    const float* __restrict__ A0, const float* __restrict__ A1,
    const float* __restrict__ st, float invM,
    const float* __restrict__ g, const float* __restrict__ be,
    const float* __restrict__ W, const float* __restrict__ bias,
    const float* __restrict__ bias2, const float* __restrict__ resid,
    float* __restrict__ out_raw, float* __restrict__ out_elu,
    float* __restrict__ stE, float* __restrict__ stR, int M, int K)
{
  __shared__ float As[16][33];
  __shared__ float Ws[16*128];        // reused as 16x128 stats scratch in epilogue
  __shared__ float ab[256], bb[256];
  int tid = threadIdx.x;
  if(tid < K){
    float mean = st[tid]*invM;
    float var  = fmaxf(st[256+tid]*invM - mean*mean, 0.f);
    float aa   = g[tid]*rsqrtf(var + 1e-5f);
    ab[tid] = aa; bb[tid] = be[tid] - mean*aa;
  }
  __syncthreads();
  int tx = tid & 15, ty = tid >> 4;      // thread owns rows ty*2,ty*2+1; cols tx*8..+7
  int m0 = blockIdx.x * 32;
  float acc[2][8] = {};
  int lk = tid & 15, lr = (tid >> 4) * 2;
  for(int kb=0; kb<K; kb+=16){
    int kg = kb + lk;
    const float* src = A0; int kk = kg;
    if(A1 && kg >= 128){ src = A1; kk = kg - 128; }
    float aa = ab[kg], b0 = bb[kg];
    #pragma unroll
    for(int r=0;r<2;++r){
      int row = m0 + lr + r;
      As[lk][lr+r] = (row < M) ? fmaf(src[row*128 + kk], aa, b0) : 0.f;
    }
    #pragma unroll
    for(int p=0;p<8;++p){
      int idx = tid + p*256;
      Ws[idx] = W[kb*128 + idx];
    }
    __syncthreads();
    #pragma unroll
    for(int kk2=0;kk2<16;++kk2){
      float a0 = As[kk2][ty*2], a1 = As[kk2][ty*2+1];
      const float4 w0 = *(const float4*)&Ws[kk2*128 + tx*8];
      const float4 w1 = *(const float4*)&Ws[kk2*128 + tx*8 + 4];
      acc[0][0]+=a0*w0.x; acc[0][1]+=a0*w0.y; acc[0][2]+=a0*w0.z; acc[0][3]+=a0*w0.w;
      acc[0][4]+=a0*w1.x; acc[0][5]+=a0*w1.y; acc[0][6]+=a0*w1.z; acc[0][7]+=a0*w1.w;
      acc[1][0]+=a1*w0.x; acc[1][1]+=a1*w0.y; acc[1][2]+=a1*w0.z; acc[1][3]+=a1*w0.w;
      acc[1][4]+=a1*w1.x; acc[1][5]+=a1*w1.y; acc[1][6]+=a1*w1.z; acc[1][7]+=a1*w1.w;
    }
    __syncthreads();
  }
  int row0 = m0 + ty*2;
  bool ok0 = row0 < M, ok1 = row0+1 < M;
  float vraw[2][8], velu[2][8];
  #pragma unroll
  for(int c=0;c<8;++c){
    int j = tx*8 + c;
    float bsum = bias[j] + (bias2 ? bias2[j] : 0.f);
    float v0 = acc[0][c] + bsum;
    float v1 = acc[1][c] + bsum;
    if(resid){
      if(ok0) v0 += resid[row0*128 + j];
      if(ok1) v1 += resid[(row0+1)*128 + j];
    }
    vraw[0][c]=v0; vraw[1][c]=v1;
    velu[0][c]=eluf(v0); velu[1][c]=eluf(v1);
  }
  #pragma unroll
  for(int r=0;r<2;++r){
    int row = row0 + r;
    if(row >= M) continue;
    if(out_raw){
      float4* p0 = (float4*)&out_raw[row*128 + tx*8];
      p0[0] = make_float4(vraw[r][0],vraw[r][1],vraw[r][2],vraw[r][3]);
      p0[1] = make_float4(vraw[r][4],vraw[r][5],vraw[r][6],vraw[r][7]);
    }
    if(out_elu){
      float4* p0 = (float4*)&out_elu[row*128 + tx*8];
      p0[0] = make_float4(velu[r][0],velu[r][1],velu[r][2],velu[r][3]);
      p0[1] = make_float4(velu[r][4],velu[r][5],velu[r][6],velu[r][7]);
    }
  }
  if(stE){
    #pragma unroll
    for(int c=0;c<8;++c)
      Ws[ty*128 + tx*8 + c] = (ok0?velu[0][c]:0.f) + (ok1?velu[1][c]:0.f);
    __syncthreads();
    if(tid<128){ float s=0; for(int r2=0;r2<16;++r2) s += Ws[r2*128+tid]; atomicAdd(&stE[tid], s); }
    __syncthreads();
    #pragma unroll
    for(int c=0;c<8;++c){
      float a = ok0?velu[0][c]:0.f, b = ok1?velu[1][c]:0.f;
      Ws[ty*128 + tx*8 + c] = a*a + b*b;
    }
    __syncthreads();
    if(tid<128){ float s=0; for(int r2=0;r2<16;++r2) s += Ws[r2*128+tid]; atomicAdd(&stE[256+tid], s); }
    __syncthreads();
  }
  if(stR){
    #pragma unroll
    for(int c=0;c<8;++c)
      Ws[ty*128 + tx*8 + c] = (ok0?vraw[0][c]:0.f) + (ok1?vraw[1][c]:0.f);
    __syncthreads();
    if(tid<128){ float s=0; for(int r2=0;r2<16;++r2) s += Ws[r2*128+tid]; atomicAdd(&stR[tid], s); }
    __syncthreads();
    #pragma unroll
    for(int c=0;c<8;++c){
      float a = ok0?vraw[0][c]:0.f, b = ok1?vraw[1][c]:0.f;
      Ws[ty*128 + tx*8 + c] = a*a + b*b;
    }
    __syncthreads();
    if(tid<128){ float s=0; for(int r2=0;r2<16;++r2) s += Ws[r2*128+tid]; atomicAdd(&stR[256+tid], s); }
  }
}

// ---------------- final: BN(v) @ W_out + b_out, elu ------------------
__global__ void final_kernel(const float* __restrict__ v_raw, const float* __restrict__ st,
                             const float* __restrict__ g2, const float* __restrict__ be2,
                             const float* __restrict__ W_out, const float* __restrict__ b_out,
                             float* __restrict__ out){
  __shared__ float pool[256];
  int tid = threadIdx.x; int half = tid>>7, k = tid&127;
  float mean = st[k]*(1.f/N_V);
  float var = fmaxf(st[256+k]*(1.f/N_V) - mean*mean, 0.f);
  float aa = g2[k]*rsqrtf(var+1e-5f);
  float scale = aa*W_out[k];
  float cons = (be2[k]-mean*aa)*W_out[k];
  int r = blockIdx.x*2 + half;          // 2500 blocks, N_V even
  float val = v_raw[r*128+k]*scale + cons;
  pool[tid]=val; __syncthreads();
  for(int s=64;s>=1;s>>=1){ if(k<s) pool[tid]+=pool[tid+s]; __syncthreads(); }
  if(k==0) out[r] = eluf(pool[tid] + b_out[0]);
}

extern "C" void kernel_launch(void* const* d_in, const int* in_sizes, int n_in,
                              void* d_out, int out_size, void* d_ws, size_t ws_size,
                              hipStream_t stream){
  const float* inputs  = (const float*)d_in[0];
  const int*   Di_rows = (const int*)d_in[2];
  const int*   Di_cols = (const int*)d_in[3];
  const float* Di_vals = (const float*)d_in[4];
  const int*   DiA_rows= (const int*)d_in[5];
  const int*   DiA_cols= (const int*)d_in[6];
  const float* DiA_vals= (const float*)d_in[7];
  const float* W_in = (const float*)d_in[8];  const float* b_in = (const float*)d_in[9];
  const float* g0  = (const float*)d_in[10];  const float* be0 = (const float*)d_in[11];
  const float* W0  = (const float*)d_in[12];  const float* b0  = (const float*)d_in[13];
  const float* g1  = (const float*)d_in[14];  const float* be1 = (const float*)d_in[15];
  const float* Wl1 = (const float*)d_in[16];  const float* bl1 = (const float*)d_in[17];
  const float* g2  = (const float*)d_in[18];  const float* be2 = (const float*)d_in[19];
  const float* W_out = (const float*)d_in[20]; const float* b_out = (const float*)d_in[21];

  float* ws = (float*)d_ws;
  float* v_raw = ws;                       // 640000
  float* elu_v = ws + 640000;              // 640000
  float* elu_f = ws + 1280000;             // 1280000
  float* Dv    = ws + 2560000;             // 1280000 (elu_x1 alias on odd layers)
  float* DAf   = ws + 3840000;             // 640000
  float* st    = ws + 4480000;             // 64*512
  float* oddb  = ws + 4512768;             // 7680
  int* Di_ptr  = (int*)(ws + 4520448);     // 40001
  int* DA_ptr  = (int*)(ws + 4560449);     // 20001
  int* Di_cur  = (int*)(ws + 4580450);     // 40000  } contiguous for one memset
  int* DA_cur  = (int*)(ws + 4620450);     // 20000  }
  int* Di_colss= (int*)(ws + 4640450);     // 480000
  float* Di_valss =     ws + 5120450;      // 480000
  int* DA_colss= (int*)(ws + 5600450);     // 480000
  float* DA_valss =     ws + 6080450;      // 480000
  int* bsumDi  = (int*)(ws + 6560450);     // 256
  int* bsumDA  = (int*)(ws + 6560706);     // 128

  hipMemsetAsync(st, 0, (size_t)64*512*sizeof(float), stream);
  hipMemsetAsync(elu_f, 0, (size_t)1280000*sizeof(float), stream);
  hipMemsetAsync(Di_cur, 0, (size_t)60000*sizeof(int), stream);

  hist_both<<<1875, 256, 0, stream>>>(Di_rows, DiA_rows, Di_cur, DA_cur);
  chunkscan<<<236, 256, 0, stream>>>(Di_cur, Di_ptr, DA_cur, DA_ptr, bsumDi, bsumDA);
  topscan<<<2, 256, 0, stream>>>(bsumDi, bsumDA);
  addback<<<236, 256, 0, stream>>>(Di_ptr, Di_cur, bsumDi, DA_ptr, DA_cur, bsumDA);
  scatter_both<<<1875, 256, 0, stream>>>(Di_rows, Di_cols, Di_vals, Di_cur, Di_colss, Di_valss,
                                         DiA_rows, DiA_cols, DiA_vals, DA_cur, DA_colss, DA_valss);
  conv1_kernel<<<640, 256, 0, stream>>>(inputs, W_in, b_in, be0, W0, be1, Wl1,
                                        v_raw, elu_v, st + 512, oddb);

  for(int i=0;i<LAYERS;++i){
    if((i&1)==0){
      float* S0  = st + (size_t)(2*i)*512;
      float* S1b = st + (size_t)(2*i+1)*512;
      spmm_bn<<<640, 256, 0, stream>>>(Di_ptr, Di_colss, Di_valss, elu_v, Dv, 40000, S0);
      gemm_bn<<<313, 256, 0, stream>>>(elu_f, Dv, S0, 1.f/N_F, g0+i*256, be0+i*256,
                                       W0+(size_t)i*32768, b0+i*128, nullptr,
                                       nullptr, nullptr, elu_f,
                                       st+(size_t)(2*(i+2))*512, nullptr, N_F, 256);
      spmm_bn<<<640, 256, 0, stream>>>(DA_ptr, DA_colss, DA_valss, elu_f, DAf, 20000, S1b);
      gemm_bn<<<157, 256, 0, stream>>>(elu_v, DAf, S1b, 1.f/N_V, g1+i*256, be1+i*256,
                                       Wl1+(size_t)i*32768, bl1+i*128, nullptr,
                                       v_raw, v_raw, elu_v,
                                       st+(size_t)(2*(i+1))*512, nullptr, N_V, 256);
    } else {
      float* S0  = st + (size_t)(2*i)*512;
      float* S1b = st + (size_t)(2*i+1)*512;
      float* elu_x1 = Dv;
      gemm_bn<<<157, 256, 0, stream>>>(elu_v, nullptr, S0, 1.f/N_V, g0+i*256, be0+i*256,
                                       W0+(size_t)i*32768, b0+i*128, oddb+i*256,
                                       nullptr, nullptr, elu_x1,
                                       S1b, nullptr, N_V, 128);
      float* stE = (i==LAYERS-1) ? nullptr : st+(size_t)(2*i+3)*512;
      float* stR = (i==LAYERS-1) ? st+(size_t)62*512 : nullptr;
      gemm_bn<<<157, 256, 0, stream>>>(elu_x1, nullptr, S1b, 1.f/N_V, g1+i*256, be1+i*256,
                                       Wl1+(size_t)i*32768, bl1+i*128, oddb+i*256+128,
                                       v_raw, v_raw, elu_v,
                                       stE, stR, N_V, 128);
    }
  }
  final_kernel<<<2500, 256, 0, stream>>>(v_raw, st+(size_t)62*512, g2, be2, W_out, b_out,
                                         (float*)d_out);
}

// Round 5
// 3142.144 us; speedup vs baseline: 3.3676x; 1.2163x over previous
//
#include <hip/hip_runtime.h>
#include <math.h>

#define N_V 5000
#define N_F 10000
#define NNZ 480000
#define LAYERS 30

typedef short short8 __attribute__((ext_vector_type(8)));
typedef float f32x4 __attribute__((ext_vector_type(4)));
union BFu { uint4 u; short8 s8; short s[8]; };

__device__ __forceinline__ float eluf(float x){ return x>0.f ? x : expm1f(x); }
__device__ __forceinline__ short f2bf(float f){
  unsigned u = __float_as_uint(f);
  unsigned r = (u + 0x7fffu + ((u>>16)&1u)) >> 16;
  return (short)r;
}

// ---------------- CSR build ----------------
__global__ void hist_both(const int* __restrict__ Di_rows, const int* __restrict__ DiA_rows,
                          int* __restrict__ Di_cur, int* __restrict__ DA_cur){
  int e = blockIdx.x*256 + threadIdx.x;
  if(e < NNZ){
    atomicAdd(&Di_cur[Di_rows[e]], 1);
    atomicAdd(&DA_cur[DiA_rows[e]], 1);
  }
}

__global__ void chunkscan(const int* __restrict__ Di_cur, int* __restrict__ Di_ptr,
                          const int* __restrict__ DA_cur, int* __restrict__ DA_ptr,
                          int* __restrict__ bsumDi, int* __restrict__ bsumDA){
  __shared__ int ish[256];
  int b = blockIdx.x, tid = threadIdx.x;
  const int nchDi = 157;
  const int* hist; int* optr; int n; int cb; int* bs;
  if(b < nchDi){ hist=Di_cur; optr=Di_ptr; n=40000; cb=b; bs=bsumDi; }
  else { hist=DA_cur; optr=DA_ptr; n=20000; cb=b-nchDi; bs=bsumDA; }
  int i = cb*256 + tid;
  int v = (i<n)? hist[i] : 0;
  ish[tid]=v; __syncthreads();
  for(int off=1; off<256; off<<=1){
    int t = (tid>=off)? ish[tid-off] : 0;
    __syncthreads(); ish[tid]+=t; __syncthreads();
  }
  if(i<n) optr[i] = ish[tid]-v;
  if(tid==255) bs[cb]=ish[255];
}

__global__ void topscan(int* __restrict__ bsumDi, int* __restrict__ bsumDA){
  __shared__ int ish[256];
  int tid=threadIdx.x;
  int* bs = (blockIdx.x==0) ? bsumDi : bsumDA;
  int n  = (blockIdx.x==0) ? 157 : 79;
  int v = (tid<n)? bs[tid] : 0;
  ish[tid]=v; __syncthreads();
  for(int off=1; off<256; off<<=1){
    int t=(tid>=off)? ish[tid-off]:0;
    __syncthreads(); ish[tid]+=t; __syncthreads();
  }
  if(tid<n) bs[tid]=ish[tid]-v;
}

__global__ void addback(int* __restrict__ Di_ptr, int* __restrict__ Di_cur,
                        const int* __restrict__ bsumDi,
                        int* __restrict__ DA_ptr, int* __restrict__ DA_cur,
                        const int* __restrict__ bsumDA){
  int stride = gridDim.x*256;
  int base = blockIdx.x*256 + threadIdx.x;
  for(int i=base;i<40000;i+=stride){ int v=Di_ptr[i]+bsumDi[i>>8]; Di_ptr[i]=v; Di_cur[i]=v; }
  for(int i=base;i<20000;i+=stride){ int v=DA_ptr[i]+bsumDA[i>>8]; DA_ptr[i]=v; DA_cur[i]=v; }
  if(base==0){ Di_ptr[40000]=NNZ; DA_ptr[20000]=NNZ; }
}

// scatter only the 4-byte permutation index (1/4 the random-write traffic)
__global__ void scatter_perm(const int* __restrict__ Di_rows, int* __restrict__ Di_cur,
                             int* __restrict__ Di_perm,
                             const int* __restrict__ DiA_rows, int* __restrict__ DA_cur,
                             int* __restrict__ DA_perm){
  int e = blockIdx.x*256 + threadIdx.x;
  if(e >= NNZ) return;
  int pos = atomicAdd(&Di_cur[Di_rows[e]], 1);
  Di_perm[pos] = e;
  pos = atomicAdd(&DA_cur[DiA_rows[e]], 1);
  DA_perm[pos] = e;
}

// sequential writes, random (L2-resident) reads
__global__ void gather_sorted(const int* __restrict__ Di_perm, const int* __restrict__ Di_cols,
                              const float* __restrict__ Di_vals, int* __restrict__ Di_colss,
                              float* __restrict__ Di_valss,
                              const int* __restrict__ DA_perm, const int* __restrict__ DiA_cols,
                              const float* __restrict__ DiA_vals, int* __restrict__ DA_colss,
                              float* __restrict__ DA_valss){
  int p = blockIdx.x*256 + threadIdx.x;
  if(p >= NNZ) return;
  int e = Di_perm[p];
  Di_colss[p] = Di_cols[e]; Di_valss[p] = Di_vals[e];
  e = DA_perm[p];
  DA_colss[p] = DiA_cols[e]; DA_valss[p] = DiA_vals[e];
}

// ---------------- weight convert: Wt[(2i+m)*128 + n][k] = bf16(W_m[i][k][n]) ----
__global__ void wconv(const float* __restrict__ W0, const float* __restrict__ Wl1,
                      short* __restrict__ Wt){
  int b = blockIdx.x;            // 60 = i*2+m
  int i = b>>1, m = b&1;
  const float* W = (m ? Wl1 : W0) + (size_t)i*32768;
  short* out = Wt + (size_t)b*32768;
  int k = threadIdx.x;           // 256
  for(int n=0;n<128;++n)
    out[n*256 + k] = f2bf(W[k*128 + n]);
}

// ---------------- conv1 (+ elu stats) + odd-bias precompute ----
__global__ void conv1_kernel(const float* __restrict__ in, const float* __restrict__ W_in,
                             const float* __restrict__ b_in,
                             const float* __restrict__ be0, const float* __restrict__ W0,
                             const float* __restrict__ be1, const float* __restrict__ Wl1,
                             float* __restrict__ v_raw, float* __restrict__ elu_v,
                             float* __restrict__ st1, float* __restrict__ oddb){
  __shared__ float pool[256];
  int tid = threadIdx.x;
  int stride = gridDim.x*256;
  float ls=0.f, ls2=0.f;
  for(int idx = blockIdx.x*256+tid; idx < N_V*128; idx += stride){
    int n = idx>>7, c = idx&127;
    float v = b_in[c] + in[n*3]*W_in[c] + in[n*3+1]*W_in[128+c] + in[n*3+2]*W_in[256+c];
    v_raw[idx] = v;
    float ev = eluf(v);
    elu_v[idx] = ev;
    ls += ev; ls2 += ev*ev;
  }
  int ch = tid & 127;
  pool[tid]=ls; __syncthreads();
  if(tid<128) atomicAdd(&st1[ch], pool[tid]+pool[tid+128]);
  __syncthreads();
  pool[tid]=ls2; __syncthreads();
  if(tid<128) atomicAdd(&st1[256+ch], pool[tid]+pool[tid+128]);
  for(int item = blockIdx.x*256+tid; item < LAYERS*2*128; item += stride){
    int i = item >> 8;
    int m = (item >> 7) & 1;
    int j = item & 127;
    const float* be = m ? be1 : be0;
    const float* W  = m ? Wl1 : W0;
    const float* wp = W + (size_t)i*32768 + 128*128 + j;
    const float* bp = be + i*256 + 128;
    float s = 0.f;
    for(int k=0;k<128;++k) s += bp[k]*wp[k*128];
    oddb[item] = s;
  }
}

// ---------------- SpMM (CSR gather) + fused channel stats ----
__global__ __launch_bounds__(256) void spmm_bn(
    const int* __restrict__ ptr, const int* __restrict__ colss, const float* __restrict__ valss,
    const float* __restrict__ x, float* __restrict__ y, int nrows, float* __restrict__ stslot){
  __shared__ float pool[256];
  int tid = threadIdx.x;
  int total = nrows*32;
  int stride = gridDim.x*256;
  float ls=0.f, ls2=0.f;
  for(int idx = blockIdx.x*256 + tid; idx < total; idx += stride){
    int row = idx>>5, j = idx&31;
    int s = ptr[row], e = ptr[row+1];
    float acc = 0.f;
    for(int i=s;i<e;++i) acc += valss[i]*x[(colss[i]<<5) + j];
    y[idx] = acc;
    ls += acc; ls2 += acc*acc;
  }
  int ch = tid & 127;
  pool[tid] = ls; __syncthreads();
  if(tid<128) atomicAdd(&stslot[128+ch], pool[tid]+pool[tid+128]);
  __syncthreads();
  pool[tid] = ls2; __syncthreads();
  if(tid<128) atomicAdd(&stslot[384+ch], pool[tid]+pool[tid+128]);
}

// ---------------- MFMA GEMM: out[M,128] = BN(concat(A0,A1)) @ W + biases (+resid) ----
// Block 256 thr = 4 waves. Tile 32 rows x 128 cols: wave w -> rows (w&1)*16, cols (w>>1)*64.
// A frag: m=lane&15, k=quad*8+j (fp32 global load + BN + bf16 cvt, no LDS).
// B frag: n=lane&15, k=quad*8+j (16B load from bf16 transposed Wt[n][k]).
// D frag: col=lane&15, row=quad*4+reg.
__global__ __launch_bounds__(256) void gemm_mfma(
    const float* __restrict__ A0, const float* __restrict__ A1,
    const float* __restrict__ st, float invM,
    const float* __restrict__ g, const float* __restrict__ be,
    const short* __restrict__ Wt, const float* __restrict__ bias,
    const float* __restrict__ bias2, const float* __restrict__ resid,
    float* __restrict__ out_raw, float* __restrict__ out_elu,
    float* __restrict__ stE, float* __restrict__ stR, int M, int K)
{
  __shared__ float ab[256], bb[256];
  __shared__ float sE[128], sE2[128], sR[128], sR2[128];
  int tid = threadIdx.x;
  if(tid < K){
    float mean = st[tid]*invM;
    float var  = fmaxf(st[256+tid]*invM - mean*mean, 0.f);
    float aa   = g[tid]*rsqrtf(var + 1e-5f);
    ab[tid] = aa; bb[tid] = be[tid] - mean*aa;
  }
  if(tid < 128){ sE[tid]=0.f; sE2[tid]=0.f; sR[tid]=0.f; sR2[tid]=0.f; }
  __syncthreads();

  int wave = tid>>6, lane = tid&63;
  int ln = lane&15, q = lane>>4;
  int r0 = blockIdx.x*32 + (wave&1)*16;
  int c0 = (wave>>1)*64;
  int kq = q*8;
  int arow = r0 + ln;
  bool aok = arow < M;

  f32x4 acc[4] = {};
  for(int kb=0; kb<K; kb+=32){
    int kg = kb + kq;
    const float* src = A0; int kk = kg;
    if(A1 && kg >= 128){ src = A1; kk = kg - 128; }
    float av[8];
    if(aok){
      float4 x0 = *(const float4*)&src[arow*128 + kk];
      float4 x1 = *(const float4*)&src[arow*128 + kk + 4];
      av[0]=x0.x; av[1]=x0.y; av[2]=x0.z; av[3]=x0.w;
      av[4]=x1.x; av[5]=x1.y; av[6]=x1.z; av[7]=x1.w;
    } else {
      #pragma unroll
      for(int j2=0;j2<8;++j2) av[j2]=0.f;
    }
    BFu af;
    #pragma unroll
    for(int j2=0;j2<8;++j2) af.s[j2] = f2bf(fmaf(av[j2], ab[kg+j2], bb[kg+j2]));
    #pragma unroll
    for(int nb=0;nb<4;++nb){
      int n = c0 + nb*16 + ln;
      BFu bf; bf.u = *(const uint4*)&Wt[n*256 + kb + kq];
      acc[nb] = __builtin_amdgcn_mfma_f32_16x16x32_bf16(af.s8, bf.s8, acc[nb], 0, 0, 0);
    }
  }

  int rbase = r0 + q*4;
  bool wantR = (stR != nullptr);
  #pragma unroll
  for(int nb=0;nb<4;++nb){
    int col = c0 + nb*16 + ln;
    float bsum = bias[col] + (bias2 ? bias2[col] : 0.f);
    float s=0.f, s2=0.f, rs=0.f, rs2=0.f;
    #pragma unroll
    for(int reg=0;reg<4;++reg){
      int row = rbase + reg;
      bool ok = row < M;
      float v = acc[nb][reg] + bsum;
      if(resid && ok) v += resid[row*128 + col];
      float ve = eluf(v);
      if(ok){
        if(out_raw) out_raw[row*128 + col] = v;
        if(out_elu) out_elu[row*128 + col] = ve;
        s += ve; s2 += ve*ve;
        if(wantR){ rs += v; rs2 += v*v; }
      }
    }
    s  += __shfl_xor(s, 16);  s  += __shfl_xor(s, 32);
    s2 += __shfl_xor(s2, 16); s2 += __shfl_xor(s2, 32);
    if(wantR){
      rs  += __shfl_xor(rs, 16);  rs  += __shfl_xor(rs, 32);
      rs2 += __shfl_xor(rs2, 16); rs2 += __shfl_xor(rs2, 32);
    }
    if(q==0){
      atomicAdd(&sE[col], s); atomicAdd(&sE2[col], s2);
      if(wantR){ atomicAdd(&sR[col], rs); atomicAdd(&sR2[col], rs2); }
    }
  }
  __syncthreads();
  if(tid < 128){
    if(stE){ atomicAdd(&stE[tid], sE[tid]); atomicAdd(&stE[256+tid], sE2[tid]); }
    if(stR){ atomicAdd(&stR[tid], sR[tid]); atomicAdd(&stR[256+tid], sR2[tid]); }
  }
}

// ---------------- final: BN(v) @ W_out + b_out, elu ------------------
__global__ void final_kernel(const float* __restrict__ v_raw, const float* __restrict__ st,
                             const float* __restrict__ g2, const float* __restrict__ be2,
                             const float* __restrict__ W_out, const float* __restrict__ b_out,
                             float* __restrict__ out){
  __shared__ float pool[256];
  int tid = threadIdx.x; int half = tid>>7, k = tid&127;
  float mean = st[k]*(1.f/N_V);
  float var = fmaxf(st[256+k]*(1.f/N_V) - mean*mean, 0.f);
  float aa = g2[k]*rsqrtf(var+1e-5f);
  float scale = aa*W_out[k];
  float cons = (be2[k]-mean*aa)*W_out[k];
  int r = blockIdx.x*2 + half;
  float val = v_raw[r*128+k]*scale + cons;
  pool[tid]=val; __syncthreads();
  for(int s=64;s>=1;s>>=1){ if(k<s) pool[tid]+=pool[tid+s]; __syncthreads(); }
  if(k==0) out[r] = eluf(pool[tid] + b_out[0]);
}

extern "C" void kernel_launch(void* const* d_in, const int* in_sizes, int n_in,
                              void* d_out, int out_size, void* d_ws, size_t ws_size,
                              hipStream_t stream){
  const float* inputs  = (const float*)d_in[0];
  const int*   Di_rows = (const int*)d_in[2];
  const int*   Di_cols = (const int*)d_in[3];
  const float* Di_vals = (const float*)d_in[4];
  const int*   DiA_rows= (const int*)d_in[5];
  const int*   DiA_cols= (const int*)d_in[6];
  const float* DiA_vals= (const float*)d_in[7];
  const float* W_in = (const float*)d_in[8];  const float* b_in = (const float*)d_in[9];
  const float* g0  = (const float*)d_in[10];  const float* be0 = (const float*)d_in[11];
  const float* W0  = (const float*)d_in[12];  const float* b0  = (const float*)d_in[13];
  const float* g1  = (const float*)d_in[14];  const float* be1 = (const float*)d_in[15];
  const float* Wl1 = (const float*)d_in[16];  const float* bl1 = (const float*)d_in[17];
  const float* g2  = (const float*)d_in[18];  const float* be2 = (const float*)d_in[19];
  const float* W_out = (const float*)d_in[20]; const float* b_out = (const float*)d_in[21];

  float* ws = (float*)d_ws;
  float* v_raw = ws;                       // 640000
  float* elu_v = ws + 640000;              // 640000
  float* elu_f = ws + 1280000;             // 1280000
  float* Dv    = ws + 2560000;             // 1280000 (elu_x1 alias on odd layers)
  float* DAf   = ws + 3840000;             // 640000
  float* st    = ws + 4480000;             // 64*512
  float* oddb  = ws + 4512768;             // 7680
  int* Di_ptr  = (int*)(ws + 4520448);     // 40001
  int* DA_ptr  = (int*)(ws + 4560449);     // 20001
  int* Di_cur  = (int*)(ws + 4580450);     // 40000 } one memset
  int* DA_cur  = (int*)(ws + 4620450);     // 20000 }
  int* Di_colss= (int*)(ws + 4640450);     // 480000
  float* Di_valss =     ws + 5120450;      // 480000
  int* DA_colss= (int*)(ws + 5600450);     // 480000
  float* DA_valss =     ws + 6080450;      // 480000
  int* bsumDi  = (int*)(ws + 6560450);     // 256
  int* bsumDA  = (int*)(ws + 6560706);     // 128
  int* Di_perm = (int*)(ws + 6560834);     // 480000  } perm dead after gather;
  int* DA_perm = (int*)(ws + 7040834);     // 480000  } Wt aliases this region
  short* Wt    = (short*)(ws + 6560834);   // 60*32768 shorts = 983040 floats
  // end = max(7520834, 7543874) floats ~= 30.2 MB

  hipMemsetAsync(st, 0, (size_t)64*512*sizeof(float), stream);
  hipMemsetAsync(elu_f, 0, (size_t)1280000*sizeof(float), stream);
  hipMemsetAsync(Di_cur, 0, (size_t)60000*sizeof(int), stream);

  hist_both<<<1875, 256, 0, stream>>>(Di_rows, DiA_rows, Di_cur, DA_cur);
  chunkscan<<<236, 256, 0, stream>>>(Di_cur, Di_ptr, DA_cur, DA_ptr, bsumDi, bsumDA);
  topscan<<<2, 256, 0, stream>>>(bsumDi, bsumDA);
  addback<<<236, 256, 0, stream>>>(Di_ptr, Di_cur, bsumDi, DA_ptr, DA_cur, bsumDA);
  scatter_perm<<<1875, 256, 0, stream>>>(Di_rows, Di_cur, Di_perm, DiA_rows, DA_cur, DA_perm);
  gather_sorted<<<1875, 256, 0, stream>>>(Di_perm, Di_cols, Di_vals, Di_colss, Di_valss,
                                          DA_perm, DiA_cols, DiA_vals, DA_colss, DA_valss);
  wconv<<<60, 256, 0, stream>>>(W0, Wl1, Wt);   // after gather: Wt aliases perm space
  conv1_kernel<<<640, 256, 0, stream>>>(inputs, W_in, b_in, be0, W0, be1, Wl1,
                                        v_raw, elu_v, st + 512, oddb);

  for(int i=0;i<LAYERS;++i){
    if((i&1)==0){
      float* S0  = st + (size_t)(2*i)*512;
      float* S1b = st + (size_t)(2*i+1)*512;
      spmm_bn<<<640, 256, 0, stream>>>(Di_ptr, Di_colss, Di_valss, elu_v, Dv, 40000, S0);
      gemm_mfma<<<313, 256, 0, stream>>>(elu_f, Dv, S0, 1.f/N_F, g0+i*256, be0+i*256,
                                         Wt + (size_t)(2*i)*32768, b0+i*128, nullptr,
                                         nullptr, nullptr, elu_f,
                                         st+(size_t)(2*(i+2))*512, nullptr, N_F, 256);
      spmm_bn<<<640, 256, 0, stream>>>(DA_ptr, DA_colss, DA_valss, elu_f, DAf, 20000, S1b);
      gemm_mfma<<<157, 256, 0, stream>>>(elu_v, DAf, S1b, 1.f/N_V, g1+i*256, be1+i*256,
                                         Wt + (size_t)(2*i+1)*32768, bl1+i*128, nullptr,
                                         v_raw, v_raw, elu_v,
                                         st+(size_t)(2*(i+1))*512, nullptr, N_V, 256);
    } else {
      float* S0  = st + (size_t)(2*i)*512;
      float* S1b = st + (size_t)(2*i+1)*512;
      float* elu_x1 = Dv;
      gemm_mfma<<<157, 256, 0, stream>>>(elu_v, nullptr, S0, 1.f/N_V, g0+i*256, be0+i*256,
                                         Wt + (size_t)(2*i)*32768, b0+i*128, oddb+i*256,
                                         nullptr, nullptr, elu_x1,
                                         S1b, nullptr, N_V, 128);
      float* stE = (i==LAYERS-1) ? nullptr : st+(size_t)(2*i+3)*512;
      float* stR = (i==LAYERS-1) ? st+(size_t)62*512 : nullptr;
      gemm_mfma<<<157, 256, 0, stream>>>(elu_x1, nullptr, S1b, 1.f/N_V, g1+i*256, be1+i*256,
                                         Wt + (size_t)(2*i+1)*32768, bl1+i*128, oddb+i*256+128,
                                         v_raw, v_raw, elu_v,
                                         stE, stR, N_V, 128);
    }
  }
  final_kernel<<<2500, 256, 0, stream>>>(v_raw, st+(size_t)62*512, g2, be2, W_out, b_out,
                                         (float*)d_out);
}

// Round 6
// 2828.497 us; speedup vs baseline: 3.7410x; 1.1109x over previous
//
#include <hip/hip_runtime.h>
#include <math.h>

#define N_V 5000
#define N_F 10000
#define NNZ 480000
#define LAYERS 30

typedef short short8 __attribute__((ext_vector_type(8)));
typedef float f32x4 __attribute__((ext_vector_type(4)));
union BFu { uint4 u; short8 s8; short s[8]; };

__device__ __forceinline__ float eluf(float x){ return x>0.f ? x : expm1f(x); }
__device__ __forceinline__ short f2bf(float f){
  unsigned u = __float_as_uint(f);
  unsigned r = (u + 0x7fffu + ((u>>16)&1u)) >> 16;
  return (short)r;
}

// ---------------- CSR build ----------------
__global__ void hist_both(const int* __restrict__ Di_rows, const int* __restrict__ DiA_rows,
                          int* __restrict__ Di_cur, int* __restrict__ DA_cur){
  int e = blockIdx.x*256 + threadIdx.x;
  if(e < NNZ){
    atomicAdd(&Di_cur[Di_rows[e]], 1);
    atomicAdd(&DA_cur[DiA_rows[e]], 1);
  }
}

__global__ void chunkscan(const int* __restrict__ Di_cur, int* __restrict__ Di_ptr,
                          const int* __restrict__ DA_cur, int* __restrict__ DA_ptr,
                          int* __restrict__ bsumDi, int* __restrict__ bsumDA){
  __shared__ int ish[256];
  int b = blockIdx.x, tid = threadIdx.x;
  const int nchDi = 157;
  const int* hist; int* optr; int n; int cb; int* bs;
  if(b < nchDi){ hist=Di_cur; optr=Di_ptr; n=40000; cb=b; bs=bsumDi; }
  else { hist=DA_cur; optr=DA_ptr; n=20000; cb=b-nchDi; bs=bsumDA; }
  int i = cb*256 + tid;
  int v = (i<n)? hist[i] : 0;
  ish[tid]=v; __syncthreads();
  for(int off=1; off<256; off<<=1){
    int t = (tid>=off)? ish[tid-off] : 0;
    __syncthreads(); ish[tid]+=t; __syncthreads();
  }
  if(i<n) optr[i] = ish[tid]-v;
  if(tid==255) bs[cb]=ish[255];
}

__global__ void topscan(int* __restrict__ bsumDi, int* __restrict__ bsumDA){
  __shared__ int ish[256];
  int tid=threadIdx.x;
  int* bs = (blockIdx.x==0) ? bsumDi : bsumDA;
  int n  = (blockIdx.x==0) ? 157 : 79;
  int v = (tid<n)? bs[tid] : 0;
  ish[tid]=v; __syncthreads();
  for(int off=1; off<256; off<<=1){
    int t=(tid>=off)? ish[tid-off]:0;
    __syncthreads(); ish[tid]+=t; __syncthreads();
  }
  if(tid<n) bs[tid]=ish[tid]-v;
}

__global__ void addback(int* __restrict__ Di_ptr, int* __restrict__ Di_cur,
                        const int* __restrict__ bsumDi,
                        int* __restrict__ DA_ptr, int* __restrict__ DA_cur,
                        const int* __restrict__ bsumDA){
  int stride = gridDim.x*256;
  int base = blockIdx.x*256 + threadIdx.x;
  for(int i=base;i<40000;i+=stride){ int v=Di_ptr[i]+bsumDi[i>>8]; Di_ptr[i]=v; Di_cur[i]=v; }
  for(int i=base;i<20000;i+=stride){ int v=DA_ptr[i]+bsumDA[i>>8]; DA_ptr[i]=v; DA_cur[i]=v; }
  if(base==0){ Di_ptr[40000]=NNZ; DA_ptr[20000]=NNZ; }
}

__global__ void scatter_perm(const int* __restrict__ Di_rows, int* __restrict__ Di_cur,
                             int* __restrict__ Di_perm,
                             const int* __restrict__ DiA_rows, int* __restrict__ DA_cur,
                             int* __restrict__ DA_perm){
  int e = blockIdx.x*256 + threadIdx.x;
  if(e >= NNZ) return;
  int pos = atomicAdd(&Di_cur[Di_rows[e]], 1);
  Di_perm[pos] = e;
  pos = atomicAdd(&DA_cur[DiA_rows[e]], 1);
  DA_perm[pos] = e;
}

// sequential writes of packed (col,val) pairs; random reads are L2-resident
__global__ void gather_pairs(const int* __restrict__ Di_perm, const int* __restrict__ Di_cols,
                             const float* __restrict__ Di_vals, float2* __restrict__ Di_pairs,
                             const int* __restrict__ DA_perm, const int* __restrict__ DiA_cols,
                             const float* __restrict__ DiA_vals, float2* __restrict__ DA_pairs){
  int p = blockIdx.x*256 + threadIdx.x;
  if(p >= NNZ) return;
  int e = Di_perm[p];
  Di_pairs[p] = make_float2(__int_as_float(Di_cols[e]), Di_vals[e]);
  e = DA_perm[p];
  DA_pairs[p] = make_float2(__int_as_float(DiA_cols[e]), DiA_vals[e]);
}

// ---------------- weight convert: Wt[(2i+m)*128 + n][k] = bf16(W_m[i][k][n]) ----
__global__ void wconv(const float* __restrict__ W0, const float* __restrict__ Wl1,
                      short* __restrict__ Wt){
  int b = blockIdx.x;            // 60 = i*2+m
  int i = b>>1, m = b&1;
  const float* W = (m ? Wl1 : W0) + (size_t)i*32768;
  short* out = Wt + (size_t)b*32768;
  int k = threadIdx.x;           // 256
  for(int n=0;n<128;++n)
    out[n*256 + k] = f2bf(W[k*128 + n]);
}

// ---------------- conv1 (+ elu stats) + odd-bias precompute ----
__global__ void conv1_kernel(const float* __restrict__ in, const float* __restrict__ W_in,
                             const float* __restrict__ b_in,
                             const float* __restrict__ be0, const float* __restrict__ W0,
                             const float* __restrict__ be1, const float* __restrict__ Wl1,
                             float* __restrict__ v_raw, float* __restrict__ elu_v,
                             float* __restrict__ st1, float* __restrict__ oddb){
  __shared__ float pool[256];
  int tid = threadIdx.x;
  int stride = gridDim.x*256;
  float ls=0.f, ls2=0.f;
  for(int idx = blockIdx.x*256+tid; idx < N_V*128; idx += stride){
    int n = idx>>7, c = idx&127;
    float v = b_in[c] + in[n*3]*W_in[c] + in[n*3+1]*W_in[128+c] + in[n*3+2]*W_in[256+c];
    v_raw[idx] = v;
    float ev = eluf(v);
    elu_v[idx] = ev;
    ls += ev; ls2 += ev*ev;
  }
  int ch = tid & 127;
  pool[tid]=ls; __syncthreads();
  if(tid<128) atomicAdd(&st1[ch], pool[tid]+pool[tid+128]);
  __syncthreads();
  pool[tid]=ls2; __syncthreads();
  if(tid<128) atomicAdd(&st1[256+ch], pool[tid]+pool[tid+128]);
  for(int item = blockIdx.x*256+tid; item < LAYERS*2*128; item += stride){
    int i = item >> 8;
    int m = (item >> 7) & 1;
    int j = item & 127;
    const float* be = m ? be1 : be0;
    const float* W  = m ? Wl1 : W0;
    const float* wp = W + (size_t)i*32768 + 128*128 + j;
    const float* bp = be + i*256 + 128;
    float s = 0.f;
    for(int k=0;k<128;++k) s += bp[k]*wp[k*128];
    oddb[item] = s;
  }
}

// ---------------- SpMM: one wave per row, lanes = 2 edge-halves x 32 channels ----
// y[row][j] = sum_e val_e * x[col_e*32 + j]; fused channel stats -> slot second half.
__global__ __launch_bounds__(256) void spmm_bn(
    const int* __restrict__ ptr, const float2* __restrict__ pairs,
    const float* __restrict__ x, float* __restrict__ y, int nrows,
    float* __restrict__ stslot){
  __shared__ float pool[128];
  int tid = threadIdx.x;
  int w = tid>>6, lane = tid&63;
  int j = lane&31, eh = lane>>5;
  float ls=0.f, ls2=0.f;
  for(int row = blockIdx.x*4 + w; row < nrows; row += gridDim.x*4){
    int s = ptr[row], e = ptr[row+1];
    float acc = 0.f;
    int i = s + eh;
    for(; i+2 < e; i += 4){
      float2 p0 = pairs[i];
      float2 p1 = pairs[i+2];
      float x0 = x[(__float_as_int(p0.x)<<5) + j];
      float x1 = x[(__float_as_int(p1.x)<<5) + j];
      acc += p0.y*x0 + p1.y*x1;
    }
    if(i < e){
      float2 p0 = pairs[i];
      acc += p0.y * x[(__float_as_int(p0.x)<<5) + j];
    }
    acc += __shfl_xor(acc, 32);
    if(eh==0){
      y[(row<<5) + j] = acc;
      ls += acc; ls2 += acc*acc;
    }
  }
  // channel = ((row&3)<<5)|j = (w<<5)|j  (grid stride is a multiple of 4 rows)
  int ch = (w<<5) | j;
  if(eh==0) pool[ch] = ls;
  __syncthreads();
  if(tid<128) atomicAdd(&stslot[128+tid], pool[tid]);
  __syncthreads();
  if(eh==0) pool[ch] = ls2;
  __syncthreads();
  if(tid<128) atomicAdd(&stslot[384+tid], pool[tid]);
}

// ---------------- MFMA GEMM: out[M,128] = BN(concat(A0,A1)) @ W + biases (+resid) ----
// Block 256 thr = 4 waves. Tile 16 rows x 128 cols: wave w -> cols w*32..w*32+31.
// A frag: m=lane&15, k=quad*8+j (fp32 global load + BN + bf16 cvt, no LDS).
// B frag: n=lane&15, k=quad*8+j (16B load from bf16 transposed Wt[n][k]).
// D frag: col=lane&15, row=quad*4+reg.
__global__ __launch_bounds__(256) void gemm_mfma(
    const float* __restrict__ A0, const float* __restrict__ A1,
    const float* __restrict__ st, float invM,
    const float* __restrict__ g, const float* __restrict__ be,
    const short* __restrict__ Wt, const float* __restrict__ bias,
    const float* __restrict__ bias2, const float* __restrict__ resid,
    float* __restrict__ out_raw, float* __restrict__ out_elu,
    float* __restrict__ stE, float* __restrict__ stR, int M, int K)
{
  __shared__ float ab[256], bb[256];
  int tid = threadIdx.x;
  if(tid < K){
    float mean = st[tid]*invM;
    float var  = fmaxf(st[256+tid]*invM - mean*mean, 0.f);
    float aa   = g[tid]*rsqrtf(var + 1e-5f);
    ab[tid] = aa; bb[tid] = be[tid] - mean*aa;
  }
  __syncthreads();

  int wave = tid>>6, lane = tid&63;
  int ln = lane&15, q = lane>>4;
  int r0 = blockIdx.x*16;
  int c0 = wave*32;
  int kq = q*8;
  int arow = r0 + ln;
  bool aok = arow < M;

  f32x4 acc[2] = {};
  for(int kb=0; kb<K; kb+=32){
    int kg = kb + kq;
    const float* src = A0; int kk = kg;
    if(A1 && kg >= 128){ src = A1; kk = kg - 128; }
    float av[8];
    if(aok){
      float4 x0 = *(const float4*)&src[arow*128 + kk];
      float4 x1 = *(const float4*)&src[arow*128 + kk + 4];
      av[0]=x0.x; av[1]=x0.y; av[2]=x0.z; av[3]=x0.w;
      av[4]=x1.x; av[5]=x1.y; av[6]=x1.z; av[7]=x1.w;
    } else {
      #pragma unroll
      for(int j2=0;j2<8;++j2) av[j2]=0.f;
    }
    BFu af;
    #pragma unroll
    for(int j2=0;j2<8;++j2) af.s[j2] = f2bf(fmaf(av[j2], ab[kg+j2], bb[kg+j2]));
    #pragma unroll
    for(int nb=0;nb<2;++nb){
      int n = c0 + nb*16 + ln;
      BFu bf; bf.u = *(const uint4*)&Wt[n*256 + kb + kq];
      acc[nb] = __builtin_amdgcn_mfma_f32_16x16x32_bf16(af.s8, bf.s8, acc[nb], 0, 0, 0);
    }
  }

  int rbase = r0 + q*4;
  bool wantR = (stR != nullptr);
  #pragma unroll
  for(int nb=0;nb<2;++nb){
    int col = c0 + nb*16 + ln;
    float bsum = bias[col] + (bias2 ? bias2[col] : 0.f);
    float s=0.f, s2=0.f, rs=0.f, rs2=0.f;
    #pragma unroll
    for(int reg=0;reg<4;++reg){
      int row = rbase + reg;
      bool ok = row < M;
      float v = acc[nb][reg] + bsum;
      if(resid && ok) v += resid[row*128 + col];
      float ve = eluf(v);
      if(ok){
        if(out_raw) out_raw[row*128 + col] = v;
        if(out_elu) out_elu[row*128 + col] = ve;
        s += ve; s2 += ve*ve;
        if(wantR){ rs += v; rs2 += v*v; }
      }
    }
    s  += __shfl_xor(s, 16);  s  += __shfl_xor(s, 32);
    s2 += __shfl_xor(s2, 16); s2 += __shfl_xor(s2, 32);
    if(wantR){
      rs  += __shfl_xor(rs, 16);  rs  += __shfl_xor(rs, 32);
      rs2 += __shfl_xor(rs2, 16); rs2 += __shfl_xor(rs2, 32);
    }
    if(q==0){
      if(stE){ atomicAdd(&stE[col], s); atomicAdd(&stE[256+col], s2); }
      if(wantR){ atomicAdd(&stR[col], rs); atomicAdd(&stR[256+col], rs2); }
    }
  }
}

// ---------------- final: BN(v) @ W_out + b_out, elu ------------------
__global__ void final_kernel(const float* __restrict__ v_raw, const float* __restrict__ st,
                             const float* __restrict__ g2, const float* __restrict__ be2,
                             const float* __restrict__ W_out, const float* __restrict__ b_out,
                             float* __restrict__ out){
  __shared__ float pool[256];
  int tid = threadIdx.x; int half = tid>>7, k = tid&127;
  float mean = st[k]*(1.f/N_V);
  float var = fmaxf(st[256+k]*(1.f/N_V) - mean*mean, 0.f);
  float aa = g2[k]*rsqrtf(var+1e-5f);
  float scale = aa*W_out[k];
  float cons = (be2[k]-mean*aa)*W_out[k];
  int r = blockIdx.x*2 + half;
  float val = v_raw[r*128+k]*scale + cons;
  pool[tid]=val; __syncthreads();
  for(int s=64;s>=1;s>>=1){ if(k<s) pool[tid]+=pool[tid+s]; __syncthreads(); }
  if(k==0) out[r] = eluf(pool[tid] + b_out[0]);
}

extern "C" void kernel_launch(void* const* d_in, const int* in_sizes, int n_in,
                              void* d_out, int out_size, void* d_ws, size_t ws_size,
                              hipStream_t stream){
  const float* inputs  = (const float*)d_in[0];
  const int*   Di_rows = (const int*)d_in[2];
  const int*   Di_cols = (const int*)d_in[3];
  const float* Di_vals = (const float*)d_in[4];
  const int*   DiA_rows= (const int*)d_in[5];
  const int*   DiA_cols= (const int*)d_in[6];
  const float* DiA_vals= (const float*)d_in[7];
  const float* W_in = (const float*)d_in[8];  const float* b_in = (const float*)d_in[9];
  const float* g0  = (const float*)d_in[10];  const float* be0 = (const float*)d_in[11];
  const float* W0  = (const float*)d_in[12];  const float* b0  = (const float*)d_in[13];
  const float* g1  = (const float*)d_in[14];  const float* be1 = (const float*)d_in[15];
  const float* Wl1 = (const float*)d_in[16];  const float* bl1 = (const float*)d_in[17];
  const float* g2  = (const float*)d_in[18];  const float* be2 = (const float*)d_in[19];
  const float* W_out = (const float*)d_in[20]; const float* b_out = (const float*)d_in[21];

  float* ws = (float*)d_ws;
  float* v_raw = ws;                       // 640000
  float* elu_v = ws + 640000;              // 640000
  float* elu_f = ws + 1280000;             // 1280000
  float* Dv    = ws + 2560000;             // 1280000 (elu_x1 alias on odd layers)
  float* DAf   = ws + 3840000;             // 640000
  float* st    = ws + 4480000;             // 64*512
  float* oddb  = ws + 4512768;             // 7680
  int* Di_ptr  = (int*)(ws + 4520448);     // 40001
  int* DA_ptr  = (int*)(ws + 4560449);     // 20001
  int* Di_cur  = (int*)(ws + 4580450);     // 40000 } one memset
  int* DA_cur  = (int*)(ws + 4620450);     // 20000 }
  float2* Di_pairs = (float2*)(ws + 4640450);  // 960000 floats (8B-aligned: offset even)
  float2* DA_pairs = (float2*)(ws + 5600450);  // 960000 floats
  int* bsumDi  = (int*)(ws + 6560450);     // 256
  int* bsumDA  = (int*)(ws + 6560706);     // 128
  int* Di_perm = (int*)(ws + 6560834);     // 480000  } perm dead after gather;
  int* DA_perm = (int*)(ws + 7040834);     // 480000  } Wt aliases this region
  short* Wt    = (short*)(ws + 6560834);   // 60*32768 shorts = 983040 floats

  hipMemsetAsync(st, 0, (size_t)64*512*sizeof(float), stream);
  hipMemsetAsync(elu_f, 0, (size_t)1280000*sizeof(float), stream);
  hipMemsetAsync(Di_cur, 0, (size_t)60000*sizeof(int), stream);

  hist_both<<<1875, 256, 0, stream>>>(Di_rows, DiA_rows, Di_cur, DA_cur);
  chunkscan<<<236, 256, 0, stream>>>(Di_cur, Di_ptr, DA_cur, DA_ptr, bsumDi, bsumDA);
  topscan<<<2, 256, 0, stream>>>(bsumDi, bsumDA);
  addback<<<236, 256, 0, stream>>>(Di_ptr, Di_cur, bsumDi, DA_ptr, DA_cur, bsumDA);
  scatter_perm<<<1875, 256, 0, stream>>>(Di_rows, Di_cur, Di_perm, DiA_rows, DA_cur, DA_perm);
  gather_pairs<<<1875, 256, 0, stream>>>(Di_perm, Di_cols, Di_vals, Di_pairs,
                                         DA_perm, DiA_cols, DiA_vals, DA_pairs);
  wconv<<<60, 256, 0, stream>>>(W0, Wl1, Wt);   // after gather: Wt aliases perm space
  conv1_kernel<<<640, 256, 0, stream>>>(inputs, W_in, b_in, be0, W0, be1, Wl1,
                                        v_raw, elu_v, st + 512, oddb);

  for(int i=0;i<LAYERS;++i){
    if((i&1)==0){
      float* S0  = st + (size_t)(2*i)*512;
      float* S1b = st + (size_t)(2*i+1)*512;
      spmm_bn<<<1024, 256, 0, stream>>>(Di_ptr, Di_pairs, elu_v, Dv, 40000, S0);
      gemm_mfma<<<625, 256, 0, stream>>>(elu_f, Dv, S0, 1.f/N_F, g0+i*256, be0+i*256,
                                         Wt + (size_t)(2*i)*32768, b0+i*128, nullptr,
                                         nullptr, nullptr, elu_f,
                                         st+(size_t)(2*(i+2))*512, nullptr, N_F, 256);
      spmm_bn<<<512, 256, 0, stream>>>(DA_ptr, DA_pairs, elu_f, DAf, 20000, S1b);
      gemm_mfma<<<313, 256, 0, stream>>>(elu_v, DAf, S1b, 1.f/N_V, g1+i*256, be1+i*256,
                                         Wt + (size_t)(2*i+1)*32768, bl1+i*128, nullptr,
                                         v_raw, v_raw, elu_v,
                                         st+(size_t)(2*(i+1))*512, nullptr, N_V, 256);
    } else {
      float* S0  = st + (size_t)(2*i)*512;
      float* S1b = st + (size_t)(2*i+1)*512;
      float* elu_x1 = Dv;
      gemm_mfma<<<313, 256, 0, stream>>>(elu_v, nullptr, S0, 1.f/N_V, g0+i*256, be0+i*256,
                                         Wt + (size_t)(2*i)*32768, b0+i*128, oddb+i*256,
                                         nullptr, nullptr, elu_x1,
                                         S1b, nullptr, N_V, 128);
      float* stE = (i==LAYERS-1) ? nullptr : st+(size_t)(2*i+3)*512;
      float* stR = (i==LAYERS-1) ? st+(size_t)62*512 : nullptr;
      gemm_mfma<<<313, 256, 0, stream>>>(elu_x1, nullptr, S1b, 1.f/N_V, g1+i*256, be1+i*256,
                                         Wt + (size_t)(2*i+1)*32768, bl1+i*128, oddb+i*256+128,
                                         v_raw, v_raw, elu_v,
                                         stE, stR, N_V, 128);
    }
  }
  final_kernel<<<2500, 256, 0, stream>>>(v_raw, st+(size_t)62*512, g2, be2, W_out, b_out,
                                         (float*)d_out);
}